// Round 10
// baseline (282.311 us; speedup 1.0000x reference)
//
#include <hip/hip_runtime.h>
#include <hip/hip_bf16.h>

#define DEV __device__ __forceinline__

constexpr int kB = 16, kC = 32, kT = 512, kS = 128, kBC = 512, kLatent = 128;
constexpr float kEps = 1e-8f;

using bf16 = __hip_bfloat16;
using bf16x8 = __attribute__((ext_vector_type(8))) short;
using f32x4  = __attribute__((ext_vector_type(4))) float;

DEV unsigned short f2bf(float v) {
    bf16 h = __float2bfloat16(v);
    return *(unsigned short*)&h;
}

DEV void gld16(const void* g, void* l) {
    __builtin_amdgcn_global_load_lds(
        (const __attribute__((address_space(1))) unsigned*)g,
        (__attribute__((address_space(3))) unsigned*)l, 16, 0, 0);
}

// ---- per-(b,c) downsample + min/max normalize + sqrt term ----
__global__ void gaf_stats_kernel(const float* __restrict__ x_raw,
                                 float* __restrict__ xn, float* __restrict__ sq) {
    int bc = blockIdx.x;
    int s  = threadIdx.x;
    const float* xp = x_raw + (size_t)bc * kT;
    float v = 0.25f * (xp[4*s] + xp[4*s+1] + xp[4*s+2] + xp[4*s+3]);
    __shared__ float smn[kS], smx[kS];
    smn[s] = v; smx[s] = v;
    __syncthreads();
    for (int off = kS/2; off > 0; off >>= 1) {
        if (s < off) {
            smn[s] = fminf(smn[s], smn[s+off]);
            smx[s] = fmaxf(smx[s], smx[s+off]);
        }
        __syncthreads();
    }
    float mn = smn[0], mx = smx[0];
    float xv = 2.0f * (v - mn) / (mx - mn + kEps) - 1.0f;
    xv = fminf(fmaxf(xv, -1.0f), 1.0f);
    float sv = sqrtf(fminf(fmaxf(1.0f - xv*xv, 0.0f), 1.0f));
    xn[bc*kS + s] = xv;
    sq[bc*kS + s] = sv;
}

// ---- all weight transposes in ONE kernel ----
__global__ void wtrans_all_kernel(const float* __restrict__ w1,
                                  const float* __restrict__ w2,
                                  const float* __restrict__ w3,
                                  const float* __restrict__ w4,
                                  bf16* __restrict__ w1b, bf16* __restrict__ wt2,
                                  bf16* __restrict__ wt3, bf16* __restrict__ wt4) {
    int idx = blockIdx.x * blockDim.x + threadIdx.x;
    if (idx < 1024) {
        int oc = idx >> 5, k = idx & 31;
        w1b[idx] = __float2bfloat16(k < 18 ? w1[oc*18 + k] : 0.0f);
        return;
    }
    idx -= 1024;
    const float* src; bf16* dst; int CIN, COUT;
    if (idx < 18432)       { src = w2; dst = wt2; CIN = 32;  COUT = 64;  }
    else if (idx < 92160)  { idx -= 18432;  src = w3; dst = wt3; CIN = 64;  COUT = 128; }
    else if (idx < 387072) { idx -= 92160;  src = w4; dst = wt4; CIN = 128; COUT = 256; }
    else return;
    int ic = idx % CIN;
    int oc = (idx / CIN) % COUT;
    int t  = idx / (CIN * COUT);
    dst[((size_t)t * COUT + oc) * CIN + ic] = __float2bfloat16(src[((size_t)oc * CIN + ic) * 9 + t]);
}

// ---- FUSED conv1+conv2 (unchanged from round 8/9) ----
__global__ __launch_bounds__(256, 2)
void conv12_kernel(const float* __restrict__ xn, const float* __restrict__ sq,
                   const bf16* __restrict__ w1b, const float* __restrict__ b1,
                   const bf16* __restrict__ wt2, const float* __restrict__ b2,
                   bf16* __restrict__ out, int img0) {
    __shared__ float xl[kS], sl[kS];
    __shared__ __align__(16) union { short G[576][40]; short H[2][288][40]; } U;
    __shared__ __align__(16) short Bs2[3][64][32];
    __shared__ __align__(16) short W1s[32][40];

    int tid  = threadIdx.x;
    int lane = tid & 63;
    int wv   = tid >> 6;
    int mblk = blockIdx.x;
    int bz   = blockIdx.y;
    int bc   = img0 + bz;

    gld16((const char*)wt2 + 0*4096 + tid*16, (char*)Bs2 + 0*4096 + tid*16);
    gld16((const char*)wt2 + 1*4096 + tid*16, (char*)Bs2 + 1*4096 + tid*16);

    if (tid < 128) {
        xl[tid] = xn[(size_t)bc * kS + tid];
        int rr = tid >> 2, sg = tid & 3;
        *(uint4*)&W1s[rr][sg*8] = *(const uint4*)(w1b + rr*32 + sg*8);
    } else {
        sl[tid - 128] = sq[(size_t)bc * kS + (tid - 128)];
    }
    __syncthreads();

    #pragma unroll
    for (int it = 0; it < 3; ++it) {
        int idx = it * 256 + tid;
        if (idx >= 576) break;
        int trow = idx >> 6, hx = idx & 63;
        int iy = 8 * mblk + trow;
        unsigned int pk[16];
        #pragma unroll
        for (int j = 0; j < 16; ++j) pk[j] = 0u;
        if (iy < 64) {
            float xr[3], sr[3], xc[3], sc[3];
            #pragma unroll
            for (int k = 0; k < 3; ++k) {
                int iyy = 2*iy + k, ixx = 2*hx + k;
                bool vy = iyy < kS, vx = ixx < kS;
                xr[k] = vy ? xl[iyy] : 0.0f;  sr[k] = vy ? sl[iyy] : 0.0f;
                xc[k] = vx ? xl[ixx] : 0.0f;  sc[k] = vx ? sl[ixx] : 0.0f;
            }
            unsigned short gs[18];
            #pragma unroll
            for (int ky = 0; ky < 3; ++ky)
                #pragma unroll
                for (int kx = 0; kx < 3; ++kx) {
                    gs[ky*3+kx]   = f2bf(xr[ky]*xc[kx] - sr[ky]*sc[kx]);
                    gs[9+ky*3+kx] = f2bf(sr[ky]*xc[kx] - xr[ky]*sc[kx]);
                }
            #pragma unroll
            for (int j = 0; j < 9; ++j)
                pk[j] = (unsigned int)gs[2*j] | ((unsigned int)gs[2*j+1] << 16);
        }
        #pragma unroll
        for (int j = 0; j < 4; ++j) *(uint4*)&U.G[idx][j*8] = ((uint4*)pk)[j];
    }
    __syncthreads();

    f32x4 c1[9][2];
    bf16x8 w1f0 = *(const bf16x8*)&W1s[(lane & 15)][(lane>>4)*8];
    bf16x8 w1f1 = *(const bf16x8*)&W1s[16 + (lane & 15)][(lane>>4)*8];
    #pragma unroll
    for (int j = 0; j < 9; ++j) {
        int mt = 4*j + wv;
        bf16x8 af = *(const bf16x8*)&U.G[mt*16 + (lane & 15)][(lane>>4)*8];
        f32x4 zz = f32x4{0.f, 0.f, 0.f, 0.f};
        c1[j][0] = __builtin_amdgcn_mfma_f32_16x16x32_bf16(af, w1f0, zz, 0, 0, 0);
        c1[j][1] = __builtin_amdgcn_mfma_f32_16x16x32_bf16(af, w1f1, zz, 0, 0, 0);
    }
    __syncthreads();

    #pragma unroll
    for (int j = 0; j < 9; ++j) {
        int mt = 4*j + wv;
        #pragma unroll
        for (int h = 0; h < 2; ++h) {
            int oc = h*16 + (lane & 15);
            float bb = b1[oc];
            #pragma unroll
            for (int rg = 0; rg < 4; ++rg) {
                int pos = mt*16 + (lane>>4)*4 + rg;
                int trow = pos >> 6, hx = pos & 63;
                float v = fmaxf(c1[j][h][rg] + bb, 0.0f);
                if (8*mblk + trow >= 64) v = 0.0f;
                U.H[hx & 1][trow*32 + (hx >> 1)][oc] = (short)f2bf(v);
            }
        }
    }
    __syncthreads();

    f32x4 acc[2][4];
    #pragma unroll
    for (int i = 0; i < 2; ++i)
        #pragma unroll
        for (int j = 0; j < 4; ++j) acc[i][j] = f32x4{0.f, 0.f, 0.f, 0.f};

    for (int tap = 0; tap < 9; ++tap) {
        if (tap + 2 < 9)
            gld16((const char*)wt2 + (tap+2)*4096 + tid*16,
                  (char*)Bs2 + ((tap+2)%3)*4096 + tid*16);
        int ky = tap / 3, kx = tap % 3;
        int trow = 2*wv + ky;
        const short* bsl = &Bs2[tap%3][0][0];
        bf16x8 af[2], bfr[4];
        #pragma unroll
        for (int mi = 0; mi < 2; ++mi) {
            int ocol = mi*16 + (lane & 15);
            int x = 2*ocol + kx;
            bf16x8 z = {0,0,0,0,0,0,0,0};
            af[mi] = (x < 64) ? *(const bf16x8*)&U.H[kx & 1][trow*32 + (x>>1)][(lane>>4)*8] : z;
        }
        #pragma unroll
        for (int ni = 0; ni < 4; ++ni)
            bfr[ni] = *(const bf16x8*)&bsl[(ni*16 + (lane&15))*32 + (lane>>4)*8];
        #pragma unroll
        for (int mi = 0; mi < 2; ++mi)
            #pragma unroll
            for (int ni = 0; ni < 4; ++ni)
                acc[mi][ni] = __builtin_amdgcn_mfma_f32_16x16x32_bf16(af[mi], bfr[ni], acc[mi][ni], 0, 0, 0);
        __syncthreads();
    }

    int oy = 4*mblk + wv;
    #pragma unroll
    for (int ni = 0; ni < 4; ++ni) {
        int oc = ni*16 + (lane & 15);
        float b = b2[oc];
        #pragma unroll
        for (int mi = 0; mi < 2; ++mi)
            #pragma unroll
            for (int rg = 0; rg < 4; ++rg) {
                int ocol = 16*mi + (lane>>4)*4 + rg;
                float v = fmaxf(acc[mi][ni][rg] + b, 0.0f);
                out[(((size_t)bz*32 + oy)*32 + ocol)*64 + oc] = __float2bfloat16(v);
            }
    }
}

// ---- conv3: block = half-image, INPUT-RESIDENT LDS tile (implicit im2col) ----
// Tile T: [par2][r 17][colx 16][slot8][8sh] = 68 KiB, slot = icq ^ (colx&7)
// (2-way-free frag reads). B (wt3): single 8 KiB buffer, register-relay dbuf.
// LDS = 76 KiB -> 2 blocks/CU. Writes h3g in conv4's swizzled flat layout:
// [par2][iy 16][col 8][slot16][8] per image (64 KiB), slot = kq ^ col.
__global__ __launch_bounds__(256, 2)
void conv3_kernel(const bf16* __restrict__ h2, const bf16* __restrict__ wt3,
                  const float* __restrict__ b3, bf16* __restrict__ h3g) {
    __shared__ __align__(16) short T[34816];   // 68 KiB
    __shared__ __align__(16) short Bs[4096];   // 8 KiB

    int tid  = threadIdx.x;
    int lane = tid & 63;
    int wv   = tid >> 6;
    int half = blockIdx.x;        // 0/1 -> out rows 0..7 / 8..15
    int img  = blockIdx.y;
    const bf16* h2i = h2 + (size_t)img * 65536;

    // stage input tile (rows half*16 .. half*16+16), swizzled
    for (int it = 0; it < 17; ++it) {
        int o = it*256 + tid;                 // 0..4351
        int r = o >> 8, c = o & 255;
        int ix = c >> 3, icq = c & 7;
        int gr = half*16 + r;
        uint4 v = {0u,0u,0u,0u};
        if (gr < 32) v = *(const uint4*)(h2i + gr*2048 + ix*64 + icq*8);
        int dst = ((((ix&1)*17 + r)*16 + (ix>>1))*8 + (icq ^ ((ix>>1)&7)))*8;
        *(uint4*)&T[dst] = v;
    }
    // B stage 0 (tap 0, icb 0)
    int brow = tid >> 1, bseg = tid & 1;
    {
        const bf16* p = wt3 + (size_t)brow*64 + bseg*16;
        uint4 v0 = *(const uint4*)p, v1 = *(const uint4*)(p + 8);
        *(uint4*)&Bs[brow*32 + bseg*16]     = v0;
        *(uint4*)&Bs[brow*32 + bseg*16 + 8] = v1;
    }
    __syncthreads();

    f32x4 acc[2][8];
    #pragma unroll
    for (int i = 0; i < 2; ++i)
        #pragma unroll
        for (int j = 0; j < 8; ++j) acc[i][j] = f32x4{0.f,0.f,0.f,0.f};

    for (int s = 0; s < 18; ++s) {
        uint4 nb0, nb1;
        if (s + 1 < 18) {    // prefetch next B stage into regs
            int tapn = (s+1) >> 1, icbn = ((s+1) & 1) * 32;
            const bf16* p = wt3 + ((size_t)tapn*128 + brow)*64 + icbn + bseg*16;
            nb0 = *(const uint4*)p; nb1 = *(const uint4*)(p + 8);
        }
        int tap = s >> 1, icq0 = (s & 1) * 4;
        int ky = tap / 3, kx = tap % 3;
        bf16x8 af[2], bfr[8];
        #pragma unroll
        for (int mi = 0; mi < 2; ++mi) {
            int m = wv*32 + mi*16 + (lane & 15);
            int oyL = m >> 4, ox3 = m & 15;
            int iy = 2*oyL + ky, ix = 2*ox3 + kx;
            int par = ix & 1, colx = ix >> 1;
            int colc = colx > 15 ? 15 : colx;
            int addr = (((par*17 + iy)*16 + colc)*8 + ((icq0 + (lane>>4)) ^ (colc & 7)))*8;
            bf16x8 v = *(const bf16x8*)&T[addr];
            bf16x8 z = {0,0,0,0,0,0,0,0};
            af[mi] = (ix < 32) ? v : z;
        }
        #pragma unroll
        for (int ni = 0; ni < 8; ++ni)
            bfr[ni] = *(const bf16x8*)&Bs[(ni*16 + (lane&15))*32 + (lane>>4)*8];
        #pragma unroll
        for (int mi = 0; mi < 2; ++mi)
            #pragma unroll
            for (int ni = 0; ni < 8; ++ni)
                acc[mi][ni] = __builtin_amdgcn_mfma_f32_16x16x32_bf16(af[mi], bfr[ni], acc[mi][ni], 0, 0, 0);
        __syncthreads();
        if (s + 1 < 18) {
            *(uint4*)&Bs[brow*32 + bseg*16]     = nb0;
            *(uint4*)&Bs[brow*32 + bseg*16 + 8] = nb1;
            __syncthreads();
        }
    }

    // epilogue: write h3 (relu+bias) in conv4's swizzled layout
    bf16* h3o = h3g + (size_t)img * 32768;
    #pragma unroll
    for (int ni = 0; ni < 8; ++ni) {
        int oc3 = ni*16 + (lane & 15);
        float bb = b3[oc3];
        int kq = oc3 >> 3, ql = oc3 & 7;
        #pragma unroll
        for (int mi = 0; mi < 2; ++mi)
            #pragma unroll
            for (int rg = 0; rg < 4; ++rg) {
                int m = wv*32 + mi*16 + (lane>>4)*4 + rg;
                int oyL = m >> 4, ox3 = m & 15;
                int iy4 = half*8 + oyL;
                int par = ox3 & 1, col4 = ox3 >> 1;
                int slot = kq ^ col4;
                int off = ((par*16 + iy4)*8 + col4)*128 + slot*8 + ql;
                float v = fmaxf(acc[mi][ni][rg] + bb, 0.0f);
                h3o[off] = __float2bfloat16(v);
            }
    }
}

// ---- conv4: block = image; h3 resident in LDS (64 KiB, pre-swizzled layout
// staged lane-linear via gld16); B (wt4) single 16 KiB register-relay buffer.
// LDS = 80 KiB exactly -> 2 blocks/CU. Fused global-avg-pool epilogue.
__global__ __launch_bounds__(256, 2)
void conv4_kernel(const bf16* __restrict__ h3g, const bf16* __restrict__ wt4,
                  const float* __restrict__ b4, float* __restrict__ pooled,
                  int img0) {
    __shared__ __align__(16) short H3s[32768];  // 64 KiB
    __shared__ __align__(16) short Bs[8192];    // 16 KiB

    int tid  = threadIdx.x;
    int lane = tid & 63;
    int wn   = tid >> 6;
    int img  = blockIdx.x;

    // stage h3 lane-linear (layout preserved)
    const char* h3b = (const char*)(h3g + (size_t)img * 32768);
    #pragma unroll
    for (int it = 0; it < 16; ++it)
        gld16(h3b + (it*256 + tid)*16, (char*)H3s + (it*256 + tid)*16);

    // B stage 0 (tap 0, icb 0): thread t -> oc row t, 64 B
    uint4 vb[4];
    {
        const bf16* p = wt4 + (size_t)tid * 128;
        #pragma unroll
        for (int j = 0; j < 4; ++j) vb[j] = *(const uint4*)(p + j*8);
        #pragma unroll
        for (int j = 0; j < 4; ++j) *(uint4*)&Bs[tid*32 + j*8] = vb[j];
    }
    __syncthreads();

    f32x4 acc[4][4];
    #pragma unroll
    for (int i = 0; i < 4; ++i)
        #pragma unroll
        for (int j = 0; j < 4; ++j) acc[i][j] = f32x4{0.f,0.f,0.f,0.f};

    for (int s = 0; s < 36; ++s) {
        uint4 nb[4];
        if (s + 1 < 36) {
            int tapn = (s+1) >> 2, icbn = ((s+1) & 3) * 32;
            const bf16* p = wt4 + ((size_t)tapn*256 + tid)*128 + icbn;
            #pragma unroll
            for (int j = 0; j < 4; ++j) nb[j] = *(const uint4*)(p + j*8);
        }
        int tap = s >> 2;
        int ky = tap / 3, kx = tap % 3;
        int kq0 = (s & 3)*4 + (lane >> 4);
        bf16x8 af[4], bfr[4];
        #pragma unroll
        for (int mi = 0; mi < 4; ++mi) {
            int m = mi*16 + (lane & 15);
            int oy = m >> 3, ox = m & 7;
            int iy = 2*oy + ky, ix = 2*ox + kx;
            bool valid = (iy < 16) && (ix < 16);
            int iyc = iy > 15 ? 15 : iy, ixc = ix > 15 ? 15 : ix;
            int par = ixc & 1, col = ixc >> 1;
            int slot = kq0 ^ col;
            int addr = ((par*16 + iyc)*8 + col)*128 + slot*8;
            bf16x8 v = *(const bf16x8*)&H3s[addr];
            bf16x8 z = {0,0,0,0,0,0,0,0};
            af[mi] = valid ? v : z;
        }
        #pragma unroll
        for (int ni = 0; ni < 4; ++ni)
            bfr[ni] = *(const bf16x8*)&Bs[(wn*64 + ni*16 + (lane&15))*32 + (lane>>4)*8];
        #pragma unroll
        for (int mi = 0; mi < 4; ++mi)
            #pragma unroll
            for (int ni = 0; ni < 4; ++ni)
                acc[mi][ni] = __builtin_amdgcn_mfma_f32_16x16x32_bf16(af[mi], bfr[ni], acc[mi][ni], 0, 0, 0);
        __syncthreads();
        if (s + 1 < 36) {
            #pragma unroll
            for (int j = 0; j < 4; ++j) *(uint4*)&Bs[tid*32 + j*8] = nb[j];
            __syncthreads();
        }
    }

    // fused global-avg-pool: wave wn owns oc slice [wn*64, wn*64+64)
    #pragma unroll
    for (int ni = 0; ni < 4; ++ni) {
        int oc = wn*64 + ni*16 + (lane & 15);
        float bb = b4[oc];
        float ssum = 0.0f;
        #pragma unroll
        for (int mi = 0; mi < 4; ++mi)
            #pragma unroll
            for (int rg = 0; rg < 4; ++rg) ssum += fmaxf(acc[mi][ni][rg] + bb, 0.0f);
        ssum += __shfl_xor(ssum, 16);
        ssum += __shfl_xor(ssum, 32);
        if (lane < 16)
            pooled[((size_t)(img0 + img))*256 + oc] = ssum * (1.0f/64.0f);
    }
}

// ---- fused: mean over C (commutes with linear FC) + FC 256->128 ----
__global__ void poolfc_kernel(const float* __restrict__ pooled, const float* __restrict__ Wfc,
                              const float* __restrict__ bfc, float* __restrict__ out) {
    int b = blockIdx.x;
    int t = threadIdx.x;
    __shared__ float pm[256];
    #pragma unroll
    for (int q = 0; q < 2; ++q) {
        int k = q*128 + t;
        float s = 0.0f;
        #pragma unroll
        for (int c = 0; c < kC; ++c) s += pooled[((size_t)(b*kC + c))*256 + k];
        pm[k] = s * (1.0f/kC);
    }
    __syncthreads();
    float acc = bfc[t];
    for (int k = 0; k < 256; ++k) acc = fmaf(pm[k], Wfc[(size_t)k*kLatent + t], acc);
    out[(size_t)b*kLatent + t] = acc;
}

extern "C" void kernel_launch(void* const* d_in, const int* in_sizes, int n_in,
                              void* d_out, int out_size, void* d_ws, size_t ws_size,
                              hipStream_t stream) {
    const float* x_raw = (const float*)d_in[0];
    const float* W1 = (const float*)d_in[1];  const float* b1 = (const float*)d_in[2];
    const float* W2 = (const float*)d_in[3];  const float* b2 = (const float*)d_in[4];
    const float* W3 = (const float*)d_in[5];  const float* b3 = (const float*)d_in[6];
    const float* W4 = (const float*)d_in[7];  const float* b4 = (const float*)d_in[8];
    const float* Wfc = (const float*)d_in[9]; const float* bfc = (const float*)d_in[10];
    float* out = (float*)d_out;

    char* wsb = (char*)d_ws;
    float* xn     = (float*)(wsb);                      // 256 KiB
    float* sq     = (float*)(wsb + (256u<<10));         // 256 KiB
    float* pooled = (float*)(wsb + (512u<<10));         // 512 KiB
    bf16* Wt2     = (bf16*)(wsb + (1280u<<10));         // 36 KiB
    bf16* Wt3     = (bf16*)(wsb + (1316u<<10));         // 144 KiB
    bf16* Wt4     = (bf16*)(wsb + (1460u<<10));         // 576 KiB
    bf16* W1b     = (bf16*)(wsb + (2036u<<10));         // 2 KiB
    char* chunk_base = wsb + (2048u<<10);               // 2 MiB header

    // per image: h2 (128 KiB) + h3g (64 KiB)
    const size_t perH2 = 32u*32u*64u*2u, perH3 = 64u<<10;
    const size_t perImg = perH2 + perH3;
    int chunk = 4;
    for (int c = 512; c >= 4; c >>= 1) {
        if ((2048u<<10) + (size_t)c * perImg <= ws_size) { chunk = c; break; }
    }

    gaf_stats_kernel<<<kBC, kS, 0, stream>>>(x_raw, xn, sq);
    wtrans_all_kernel<<<(388096 + 255)/256, 256, 0, stream>>>(W1, W2, W3, W4, W1b, Wt2, Wt3, Wt4);

    for (int img0 = 0; img0 < kBC; img0 += chunk) {
        int nimg = chunk;
        bf16* h2  = (bf16*)chunk_base;
        bf16* h3g = (bf16*)(chunk_base + (size_t)chunk * perH2);

        conv12_kernel<<<dim3(8, nimg), 256, 0, stream>>>(xn, sq, W1b, b1, Wt2, b2, h2, img0);
        conv3_kernel<<<dim3(2, nimg), 256, 0, stream>>>(h2, Wt3, b3, h3g);
        conv4_kernel<<<nimg, 256, 0, stream>>>(h3g, Wt4, b4, pooled, img0);
    }

    poolfc_kernel<<<kB, kLatent, 0, stream>>>(pooled, Wfc, bfc, out);
}

// Round 11
// 281.267 us; speedup vs baseline: 1.0037x; 1.0037x over previous
//
#include <hip/hip_runtime.h>
#include <hip/hip_bf16.h>

#define DEV __device__ __forceinline__

constexpr int kB = 16, kC = 32, kT = 512, kS = 128, kBC = 512, kLatent = 128;
constexpr float kEps = 1e-8f;

using bf16 = __hip_bfloat16;
using bf16x8 = __attribute__((ext_vector_type(8))) short;
using f32x4  = __attribute__((ext_vector_type(4))) float;

DEV unsigned short f2bf(float v) {
    bf16 h = __float2bfloat16(v);
    return *(unsigned short*)&h;
}

DEV void gld16(const void* g, void* l) {
    __builtin_amdgcn_global_load_lds(
        (const __attribute__((address_space(1))) unsigned*)g,
        (__attribute__((address_space(3))) unsigned*)l, 16, 0, 0);
}

// B-buffer segment swizzle: logical seg sl of row r lives at physical sl^bswz(r).
// Makes both relay ds_writes and fragment ds_reads conflict-free on 32-short rows.
DEV int bswz(int row) { return (row >> 1) & 3; }

// ---- per-(b,c) downsample + min/max normalize + sqrt term ----
__global__ void gaf_stats_kernel(const float* __restrict__ x_raw,
                                 float* __restrict__ xn, float* __restrict__ sq) {
    int bc = blockIdx.x;
    int s  = threadIdx.x;
    const float* xp = x_raw + (size_t)bc * kT;
    float v = 0.25f * (xp[4*s] + xp[4*s+1] + xp[4*s+2] + xp[4*s+3]);
    __shared__ float smn[kS], smx[kS];
    smn[s] = v; smx[s] = v;
    __syncthreads();
    for (int off = kS/2; off > 0; off >>= 1) {
        if (s < off) {
            smn[s] = fminf(smn[s], smn[s+off]);
            smx[s] = fmaxf(smx[s], smx[s+off]);
        }
        __syncthreads();
    }
    float mn = smn[0], mx = smx[0];
    float xv = 2.0f * (v - mn) / (mx - mn + kEps) - 1.0f;
    xv = fminf(fmaxf(xv, -1.0f), 1.0f);
    float sv = sqrtf(fminf(fmaxf(1.0f - xv*xv, 0.0f), 1.0f));
    xn[bc*kS + s] = xv;
    sq[bc*kS + s] = sv;
}

// ---- all weight transposes in ONE kernel ----
__global__ void wtrans_all_kernel(const float* __restrict__ w1,
                                  const float* __restrict__ w2,
                                  const float* __restrict__ w3,
                                  const float* __restrict__ w4,
                                  bf16* __restrict__ w1b, bf16* __restrict__ wt2,
                                  bf16* __restrict__ wt3, bf16* __restrict__ wt4) {
    int idx = blockIdx.x * blockDim.x + threadIdx.x;
    if (idx < 1024) {
        int oc = idx >> 5, k = idx & 31;
        w1b[idx] = __float2bfloat16(k < 18 ? w1[oc*18 + k] : 0.0f);
        return;
    }
    idx -= 1024;
    const float* src; bf16* dst; int CIN, COUT;
    if (idx < 18432)       { src = w2; dst = wt2; CIN = 32;  COUT = 64;  }
    else if (idx < 92160)  { idx -= 18432;  src = w3; dst = wt3; CIN = 64;  COUT = 128; }
    else if (idx < 387072) { idx -= 92160;  src = w4; dst = wt4; CIN = 128; COUT = 256; }
    else return;
    int ic = idx % CIN;
    int oc = (idx / CIN) % COUT;
    int t  = idx / (CIN * COUT);
    dst[((size_t)t * COUT + oc) * CIN + ic] = __float2bfloat16(src[((size_t)oc * CIN + ic) * 9 + t]);
}

// ---- FUSED conv1+conv2 ----
// Bs2 staged via gld16 (lane-linear dest) with SOURCE-swizzled seg so that
// physical (row=tid>>2, sphys=tid&3) holds logical seg sphys^bswz(row);
// fragment reads then use seg q^bswz(row) -> conflict-free.
__global__ __launch_bounds__(256, 2)
void conv12_kernel(const float* __restrict__ xn, const float* __restrict__ sq,
                   const bf16* __restrict__ w1b, const float* __restrict__ b1,
                   const bf16* __restrict__ wt2, const float* __restrict__ b2,
                   bf16* __restrict__ out, int img0) {
    __shared__ float xl[kS], sl[kS];
    __shared__ __align__(16) union { short G[576][40]; short H[2][288][40]; } U;
    __shared__ __align__(16) short Bs2[3][64][32];
    __shared__ __align__(16) short W1s[32][40];

    int tid  = threadIdx.x;
    int lane = tid & 63;
    int wv   = tid >> 6;
    int mblk = blockIdx.x;
    int bz   = blockIdx.y;
    int bc   = img0 + bz;

    // swizzled gld16 source offset within one 4 KiB tap block
    int bsrc = (tid >> 2) * 64 + (((tid & 3) ^ ((tid >> 3) & 3)) * 16);
    gld16((const char*)wt2 + 0*4096 + bsrc, (char*)Bs2 + 0*4096 + tid*16);
    gld16((const char*)wt2 + 1*4096 + bsrc, (char*)Bs2 + 1*4096 + tid*16);

    if (tid < 128) {
        xl[tid] = xn[(size_t)bc * kS + tid];
        int rr = tid >> 2, sg = tid & 3;
        *(uint4*)&W1s[rr][sg*8] = *(const uint4*)(w1b + rr*32 + sg*8);
    } else {
        sl[tid - 128] = sq[(size_t)bc * kS + (tid - 128)];
    }
    __syncthreads();

    #pragma unroll
    for (int it = 0; it < 3; ++it) {
        int idx = it * 256 + tid;
        if (idx >= 576) break;
        int trow = idx >> 6, hx = idx & 63;
        int iy = 8 * mblk + trow;
        unsigned int pk[16];
        #pragma unroll
        for (int j = 0; j < 16; ++j) pk[j] = 0u;
        if (iy < 64) {
            float xr[3], sr[3], xc[3], sc[3];
            #pragma unroll
            for (int k = 0; k < 3; ++k) {
                int iyy = 2*iy + k, ixx = 2*hx + k;
                bool vy = iyy < kS, vx = ixx < kS;
                xr[k] = vy ? xl[iyy] : 0.0f;  sr[k] = vy ? sl[iyy] : 0.0f;
                xc[k] = vx ? xl[ixx] : 0.0f;  sc[k] = vx ? sl[ixx] : 0.0f;
            }
            unsigned short gs[18];
            #pragma unroll
            for (int ky = 0; ky < 3; ++ky)
                #pragma unroll
                for (int kx = 0; kx < 3; ++kx) {
                    gs[ky*3+kx]   = f2bf(xr[ky]*xc[kx] - sr[ky]*sc[kx]);
                    gs[9+ky*3+kx] = f2bf(sr[ky]*xc[kx] - xr[ky]*sc[kx]);
                }
            #pragma unroll
            for (int j = 0; j < 9; ++j)
                pk[j] = (unsigned int)gs[2*j] | ((unsigned int)gs[2*j+1] << 16);
        }
        #pragma unroll
        for (int j = 0; j < 4; ++j) *(uint4*)&U.G[idx][j*8] = ((uint4*)pk)[j];
    }
    __syncthreads();

    f32x4 c1[9][2];
    bf16x8 w1f0 = *(const bf16x8*)&W1s[(lane & 15)][(lane>>4)*8];
    bf16x8 w1f1 = *(const bf16x8*)&W1s[16 + (lane & 15)][(lane>>4)*8];
    #pragma unroll
    for (int j = 0; j < 9; ++j) {
        int mt = 4*j + wv;
        bf16x8 af = *(const bf16x8*)&U.G[mt*16 + (lane & 15)][(lane>>4)*8];
        f32x4 zz = f32x4{0.f, 0.f, 0.f, 0.f};
        c1[j][0] = __builtin_amdgcn_mfma_f32_16x16x32_bf16(af, w1f0, zz, 0, 0, 0);
        c1[j][1] = __builtin_amdgcn_mfma_f32_16x16x32_bf16(af, w1f1, zz, 0, 0, 0);
    }
    __syncthreads();

    #pragma unroll
    for (int j = 0; j < 9; ++j) {
        int mt = 4*j + wv;
        #pragma unroll
        for (int h = 0; h < 2; ++h) {
            int oc = h*16 + (lane & 15);
            float bb = b1[oc];
            #pragma unroll
            for (int rg = 0; rg < 4; ++rg) {
                int pos = mt*16 + (lane>>4)*4 + rg;
                int trow = pos >> 6, hx = pos & 63;
                float v = fmaxf(c1[j][h][rg] + bb, 0.0f);
                if (8*mblk + trow >= 64) v = 0.0f;
                U.H[hx & 1][trow*32 + (hx >> 1)][oc] = (short)f2bf(v);
            }
        }
    }
    __syncthreads();

    f32x4 acc[2][4];
    #pragma unroll
    for (int i = 0; i < 2; ++i)
        #pragma unroll
        for (int j = 0; j < 4; ++j) acc[i][j] = f32x4{0.f, 0.f, 0.f, 0.f};

    for (int tap = 0; tap < 9; ++tap) {
        if (tap + 2 < 9)
            gld16((const char*)wt2 + (tap+2)*4096 + bsrc,
                  (char*)Bs2 + ((tap+2)%3)*4096 + tid*16);
        int ky = tap / 3, kx = tap % 3;
        int trow = 2*wv + ky;
        const short* bsl = &Bs2[tap%3][0][0];
        bf16x8 af[2], bfr[4];
        #pragma unroll
        for (int mi = 0; mi < 2; ++mi) {
            int ocol = mi*16 + (lane & 15);
            int x = 2*ocol + kx;
            bf16x8 z = {0,0,0,0,0,0,0,0};
            af[mi] = (x < 64) ? *(const bf16x8*)&U.H[kx & 1][trow*32 + (x>>1)][(lane>>4)*8] : z;
        }
        #pragma unroll
        for (int ni = 0; ni < 4; ++ni) {
            int row = ni*16 + (lane & 15);
            bfr[ni] = *(const bf16x8*)&bsl[row*32 + (((lane>>4) ^ bswz(row))*8)];
        }
        #pragma unroll
        for (int mi = 0; mi < 2; ++mi)
            #pragma unroll
            for (int ni = 0; ni < 4; ++ni)
                acc[mi][ni] = __builtin_amdgcn_mfma_f32_16x16x32_bf16(af[mi], bfr[ni], acc[mi][ni], 0, 0, 0);
        __syncthreads();
    }

    int oy = 4*mblk + wv;
    #pragma unroll
    for (int ni = 0; ni < 4; ++ni) {
        int oc = ni*16 + (lane & 15);
        float b = b2[oc];
        #pragma unroll
        for (int mi = 0; mi < 2; ++mi)
            #pragma unroll
            for (int rg = 0; rg < 4; ++rg) {
                int ocol = 16*mi + (lane>>4)*4 + rg;
                float v = fmaxf(acc[mi][ni][rg] + b, 0.0f);
                out[(((size_t)bz*32 + oy)*32 + ocol)*64 + oc] = __float2bfloat16(v);
            }
    }
}

// ---- conv3: block = half-image, input-resident LDS tile (implicit im2col) ----
// B relay: coalesced j-row loads, seg-swizzled ds_writes/reads (conflict-free).
__global__ __launch_bounds__(256, 2)
void conv3_kernel(const bf16* __restrict__ h2, const bf16* __restrict__ wt3,
                  const float* __restrict__ b3, bf16* __restrict__ h3g) {
    __shared__ __align__(16) short T[34816];   // 68 KiB
    __shared__ __align__(16) short Bs[4096];   // 8 KiB

    int tid  = threadIdx.x;
    int lane = tid & 63;
    int wv   = tid >> 6;
    int half = blockIdx.x;
    int img  = blockIdx.y;
    const bf16* h2i = h2 + (size_t)img * 65536;

    // stage input tile (rows half*16 .. half*16+16), swizzled
    for (int it = 0; it < 17; ++it) {
        int o = it*256 + tid;
        int r = o >> 8, c = o & 255;
        int ix = c >> 3, icq = c & 7;
        int gr = half*16 + r;
        uint4 v = {0u,0u,0u,0u};
        if (gr < 32) v = *(const uint4*)(h2i + gr*2048 + ix*64 + icq*8);
        int dst = ((((ix&1)*17 + r)*16 + (ix>>1))*8 + (icq ^ ((ix>>1)&7)))*8;
        *(uint4*)&T[dst] = v;
    }
    // B stage 0: rows j*64+(tid>>2), logical seg sl=tid&3, swizzled write
    int sl = tid & 3, rsub = tid >> 2;
    {
        #pragma unroll
        for (int j = 0; j < 2; ++j) {
            int row = j*64 + rsub;
            uint4 v = *(const uint4*)(wt3 + (size_t)row*64 + sl*8);
            *(uint4*)&Bs[row*32 + ((sl ^ bswz(row))*8)] = v;
        }
    }
    __syncthreads();

    f32x4 acc[2][8];
    #pragma unroll
    for (int i = 0; i < 2; ++i)
        #pragma unroll
        for (int j = 0; j < 8; ++j) acc[i][j] = f32x4{0.f,0.f,0.f,0.f};

    for (int s = 0; s < 18; ++s) {
        uint4 nb[2];
        if (s + 1 < 18) {
            int tapn = (s+1) >> 1, icbn = ((s+1) & 1) * 32;
            #pragma unroll
            for (int j = 0; j < 2; ++j) {
                int row = j*64 + rsub;
                nb[j] = *(const uint4*)(wt3 + ((size_t)tapn*128 + row)*64 + icbn + sl*8);
            }
        }
        int tap = s >> 1, icq0 = (s & 1) * 4;
        int ky = tap / 3, kx = tap % 3;
        bf16x8 af[2], bfr[8];
        #pragma unroll
        for (int mi = 0; mi < 2; ++mi) {
            int m = wv*32 + mi*16 + (lane & 15);
            int oyL = m >> 4, ox3 = m & 15;
            int iy = 2*oyL + ky, ix = 2*ox3 + kx;
            int par = ix & 1, colx = ix >> 1;
            int colc = colx > 15 ? 15 : colx;
            int addr = (((par*17 + iy)*16 + colc)*8 + ((icq0 + (lane>>4)) ^ (colc & 7)))*8;
            bf16x8 v = *(const bf16x8*)&T[addr];
            bf16x8 z = {0,0,0,0,0,0,0,0};
            af[mi] = (ix < 32) ? v : z;
        }
        #pragma unroll
        for (int ni = 0; ni < 8; ++ni) {
            int row = ni*16 + (lane & 15);
            bfr[ni] = *(const bf16x8*)&Bs[row*32 + (((lane>>4) ^ bswz(row))*8)];
        }
        #pragma unroll
        for (int mi = 0; mi < 2; ++mi)
            #pragma unroll
            for (int ni = 0; ni < 8; ++ni)
                acc[mi][ni] = __builtin_amdgcn_mfma_f32_16x16x32_bf16(af[mi], bfr[ni], acc[mi][ni], 0, 0, 0);
        __syncthreads();
        if (s + 1 < 18) {
            #pragma unroll
            for (int j = 0; j < 2; ++j) {
                int row = j*64 + rsub;
                *(uint4*)&Bs[row*32 + ((sl ^ bswz(row))*8)] = nb[j];
            }
            __syncthreads();
        }
    }

    // epilogue: write h3 (relu+bias) in conv4's swizzled layout
    bf16* h3o = h3g + (size_t)img * 32768;
    #pragma unroll
    for (int ni = 0; ni < 8; ++ni) {
        int oc3 = ni*16 + (lane & 15);
        float bb = b3[oc3];
        int kq = oc3 >> 3, ql = oc3 & 7;
        #pragma unroll
        for (int mi = 0; mi < 2; ++mi)
            #pragma unroll
            for (int rg = 0; rg < 4; ++rg) {
                int m = wv*32 + mi*16 + (lane>>4)*4 + rg;
                int oyL = m >> 4, ox3 = m & 15;
                int iy4 = half*8 + oyL;
                int par = ox3 & 1, col4 = ox3 >> 1;
                int slot = kq ^ col4;
                int off = ((par*16 + iy4)*8 + col4)*128 + slot*8 + ql;
                float v = fmaxf(acc[mi][ni][rg] + bb, 0.0f);
                h3o[off] = __float2bfloat16(v);
            }
    }
}

// ---- conv4: block = image; h3 resident (64 KiB, pre-swizzled, gld16-staged);
// B relay: coalesced j-row loads + seg-swizzled writes/reads. 80 KiB LDS.
__global__ __launch_bounds__(256, 2)
void conv4_kernel(const bf16* __restrict__ h3g, const bf16* __restrict__ wt4,
                  const float* __restrict__ b4, float* __restrict__ pooled,
                  int img0) {
    __shared__ __align__(16) short H3s[32768];  // 64 KiB
    __shared__ __align__(16) short Bs[8192];    // 16 KiB

    int tid  = threadIdx.x;
    int lane = tid & 63;
    int wn   = tid >> 6;
    int img  = blockIdx.x;

    // stage h3 lane-linear (layout preserved)
    const char* h3b = (const char*)(h3g + (size_t)img * 32768);
    #pragma unroll
    for (int it = 0; it < 16; ++it)
        gld16(h3b + (it*256 + tid)*16, (char*)H3s + (it*256 + tid)*16);

    int sl = tid & 3, rsub = tid >> 2;
    // B stage 0 (tap 0, icb 0)
    {
        #pragma unroll
        for (int j = 0; j < 4; ++j) {
            int row = j*64 + rsub;
            uint4 v = *(const uint4*)(wt4 + (size_t)row*128 + sl*8);
            *(uint4*)&Bs[row*32 + ((sl ^ bswz(row))*8)] = v;
        }
    }
    __syncthreads();

    f32x4 acc[4][4];
    #pragma unroll
    for (int i = 0; i < 4; ++i)
        #pragma unroll
        for (int j = 0; j < 4; ++j) acc[i][j] = f32x4{0.f,0.f,0.f,0.f};

    for (int s = 0; s < 36; ++s) {
        uint4 nb[4];
        if (s + 1 < 36) {
            int tapn = (s+1) >> 2, icbn = ((s+1) & 3) * 32;
            #pragma unroll
            for (int j = 0; j < 4; ++j) {
                int row = j*64 + rsub;
                nb[j] = *(const uint4*)(wt4 + ((size_t)tapn*256 + row)*128 + icbn + sl*8);
            }
        }
        int tap = s >> 2;
        int ky = tap / 3, kx = tap % 3;
        int kq0 = (s & 3)*4 + (lane >> 4);
        bf16x8 af[4], bfr[4];
        #pragma unroll
        for (int mi = 0; mi < 4; ++mi) {
            int m = mi*16 + (lane & 15);
            int oy = m >> 3, ox = m & 7;
            int iy = 2*oy + ky, ix = 2*ox + kx;
            bool valid = (iy < 16) && (ix < 16);
            int iyc = iy > 15 ? 15 : iy, ixc = ix > 15 ? 15 : ix;
            int par = ixc & 1, col = ixc >> 1;
            int slot = kq0 ^ col;
            int addr = ((par*16 + iyc)*8 + col)*128 + slot*8;
            bf16x8 v = *(const bf16x8*)&H3s[addr];
            bf16x8 z = {0,0,0,0,0,0,0,0};
            af[mi] = valid ? v : z;
        }
        #pragma unroll
        for (int ni = 0; ni < 4; ++ni) {
            int row = wn*64 + ni*16 + (lane & 15);
            bfr[ni] = *(const bf16x8*)&Bs[row*32 + (((lane>>4) ^ bswz(row))*8)];
        }
        #pragma unroll
        for (int mi = 0; mi < 4; ++mi)
            #pragma unroll
            for (int ni = 0; ni < 4; ++ni)
                acc[mi][ni] = __builtin_amdgcn_mfma_f32_16x16x32_bf16(af[mi], bfr[ni], acc[mi][ni], 0, 0, 0);
        __syncthreads();
        if (s + 1 < 36) {
            #pragma unroll
            for (int j = 0; j < 4; ++j) {
                int row = j*64 + rsub;
                *(uint4*)&Bs[row*32 + ((sl ^ bswz(row))*8)] = nb[j];
            }
            __syncthreads();
        }
    }

    // fused global-avg-pool: wave wn owns oc slice [wn*64, wn*64+64)
    #pragma unroll
    for (int ni = 0; ni < 4; ++ni) {
        int oc = wn*64 + ni*16 + (lane & 15);
        float bb = b4[oc];
        float ssum = 0.0f;
        #pragma unroll
        for (int mi = 0; mi < 4; ++mi)
            #pragma unroll
            for (int rg = 0; rg < 4; ++rg) ssum += fmaxf(acc[mi][ni][rg] + bb, 0.0f);
        ssum += __shfl_xor(ssum, 16);
        ssum += __shfl_xor(ssum, 32);
        if (lane < 16)
            pooled[((size_t)(img0 + img))*256 + oc] = ssum * (1.0f/64.0f);
    }
}

// ---- fused: mean over C (commutes with linear FC) + FC 256->128 ----
__global__ void poolfc_kernel(const float* __restrict__ pooled, const float* __restrict__ Wfc,
                              const float* __restrict__ bfc, float* __restrict__ out) {
    int b = blockIdx.x;
    int t = threadIdx.x;
    __shared__ float pm[256];
    #pragma unroll
    for (int q = 0; q < 2; ++q) {
        int k = q*128 + t;
        float s = 0.0f;
        #pragma unroll
        for (int c = 0; c < kC; ++c) s += pooled[((size_t)(b*kC + c))*256 + k];
        pm[k] = s * (1.0f/kC);
    }
    __syncthreads();
    float acc = bfc[t];
    for (int k = 0; k < 256; ++k) acc = fmaf(pm[k], Wfc[(size_t)k*kLatent + t], acc);
    out[(size_t)b*kLatent + t] = acc;
}

extern "C" void kernel_launch(void* const* d_in, const int* in_sizes, int n_in,
                              void* d_out, int out_size, void* d_ws, size_t ws_size,
                              hipStream_t stream) {
    const float* x_raw = (const float*)d_in[0];
    const float* W1 = (const float*)d_in[1];  const float* b1 = (const float*)d_in[2];
    const float* W2 = (const float*)d_in[3];  const float* b2 = (const float*)d_in[4];
    const float* W3 = (const float*)d_in[5];  const float* b3 = (const float*)d_in[6];
    const float* W4 = (const float*)d_in[7];  const float* b4 = (const float*)d_in[8];
    const float* Wfc = (const float*)d_in[9]; const float* bfc = (const float*)d_in[10];
    float* out = (float*)d_out;

    char* wsb = (char*)d_ws;
    float* xn     = (float*)(wsb);                      // 256 KiB
    float* sq     = (float*)(wsb + (256u<<10));         // 256 KiB
    float* pooled = (float*)(wsb + (512u<<10));         // 512 KiB
    bf16* Wt2     = (bf16*)(wsb + (1280u<<10));         // 36 KiB
    bf16* Wt3     = (bf16*)(wsb + (1316u<<10));         // 144 KiB
    bf16* Wt4     = (bf16*)(wsb + (1460u<<10));         // 576 KiB
    bf16* W1b     = (bf16*)(wsb + (2036u<<10));         // 2 KiB
    char* chunk_base = wsb + (2048u<<10);               // 2 MiB header

    const size_t perH2 = 32u*32u*64u*2u, perH3 = 64u<<10;
    const size_t perImg = perH2 + perH3;
    int chunk = 4;
    for (int c = 512; c >= 4; c >>= 1) {
        if ((2048u<<10) + (size_t)c * perImg <= ws_size) { chunk = c; break; }
    }

    gaf_stats_kernel<<<kBC, kS, 0, stream>>>(x_raw, xn, sq);
    wtrans_all_kernel<<<(388096 + 255)/256, 256, 0, stream>>>(W1, W2, W3, W4, W1b, Wt2, Wt3, Wt4);

    for (int img0 = 0; img0 < kBC; img0 += chunk) {
        int nimg = chunk;
        bf16* h2  = (bf16*)chunk_base;
        bf16* h3g = (bf16*)(chunk_base + (size_t)chunk * perH2);

        conv12_kernel<<<dim3(8, nimg), 256, 0, stream>>>(xn, sq, W1b, b1, Wt2, b2, h2, img0);
        conv3_kernel<<<dim3(2, nimg), 256, 0, stream>>>(h2, Wt3, b3, h3g);
        conv4_kernel<<<nimg, 256, 0, stream>>>(h3g, Wt4, b4, pooled, img0);
    }

    poolfc_kernel<<<kB, kLatent, 0, stream>>>(pooled, Wfc, bfc, out);
}

// Round 12
// 262.877 us; speedup vs baseline: 1.0739x; 1.0700x over previous
//
#include <hip/hip_runtime.h>
#include <hip/hip_bf16.h>

#define DEV __device__ __forceinline__

constexpr int kB = 16, kC = 32, kT = 512, kS = 128, kBC = 512, kLatent = 128;
constexpr float kEps = 1e-8f;

using bf16 = __hip_bfloat16;
using bf16x8 = __attribute__((ext_vector_type(8))) short;
using f32x4  = __attribute__((ext_vector_type(4))) float;

DEV unsigned short f2bf(float v) {
    bf16 h = __float2bfloat16(v);
    return *(unsigned short*)&h;
}

DEV void gld16(const void* g, void* l) {
    __builtin_amdgcn_global_load_lds(
        (const __attribute__((address_space(1))) unsigned*)g,
        (__attribute__((address_space(3))) unsigned*)l, 16, 0, 0);
}

// ---- per-(b,c) downsample + min/max normalize + sqrt term ----
__global__ void gaf_stats_kernel(const float* __restrict__ x_raw,
                                 float* __restrict__ xn, float* __restrict__ sq) {
    int bc = blockIdx.x;
    int s  = threadIdx.x;
    const float* xp = x_raw + (size_t)bc * kT;
    float v = 0.25f * (xp[4*s] + xp[4*s+1] + xp[4*s+2] + xp[4*s+3]);
    __shared__ float smn[kS], smx[kS];
    smn[s] = v; smx[s] = v;
    __syncthreads();
    for (int off = kS/2; off > 0; off >>= 1) {
        if (s < off) {
            smn[s] = fminf(smn[s], smn[s+off]);
            smx[s] = fmaxf(smx[s], smx[s+off]);
        }
        __syncthreads();
    }
    float mn = smn[0], mx = smx[0];
    float xv = 2.0f * (v - mn) / (mx - mn + kEps) - 1.0f;
    xv = fminf(fmaxf(xv, -1.0f), 1.0f);
    float sv = sqrtf(fminf(fmaxf(1.0f - xv*xv, 0.0f), 1.0f));
    xn[bc*kS + s] = xv;
    sq[bc*kS + s] = sv;
}

// ---- all weight transposes in ONE kernel ----
__global__ void wtrans_all_kernel(const float* __restrict__ w1,
                                  const float* __restrict__ w2,
                                  const float* __restrict__ w3,
                                  const float* __restrict__ w4,
                                  bf16* __restrict__ w1b, bf16* __restrict__ wt2,
                                  bf16* __restrict__ wt3, bf16* __restrict__ wt4) {
    int idx = blockIdx.x * blockDim.x + threadIdx.x;
    if (idx < 1024) {
        int oc = idx >> 5, k = idx & 31;
        w1b[idx] = __float2bfloat16(k < 18 ? w1[oc*18 + k] : 0.0f);
        return;
    }
    idx -= 1024;
    const float* src; bf16* dst; int CIN, COUT;
    if (idx < 18432)       { src = w2; dst = wt2; CIN = 32;  COUT = 64;  }
    else if (idx < 92160)  { idx -= 18432;  src = w3; dst = wt3; CIN = 64;  COUT = 128; }
    else if (idx < 387072) { idx -= 92160;  src = w4; dst = wt4; CIN = 128; COUT = 256; }
    else return;
    int ic = idx % CIN;
    int oc = (idx / CIN) % COUT;
    int t  = idx / (CIN * COUT);
    dst[((size_t)t * COUT + oc) * CIN + ic] = __float2bfloat16(src[((size_t)oc * CIN + ic) * 9 + t]);
}

// ---- FUSED conv1+conv2 ----
// Phase 2 K-loop is BARRIER-FREE: A (h1) is LDS-resident read-only; B (wt2,
// 36 KiB, L1/L2-hot) is loaded straight into registers with distance-1 prefetch.
__global__ __launch_bounds__(256, 3)
void conv12_kernel(const float* __restrict__ xn, const float* __restrict__ sq,
                   const bf16* __restrict__ w1b, const float* __restrict__ b1,
                   const bf16* __restrict__ wt2, const float* __restrict__ b2,
                   bf16* __restrict__ out, int img0) {
    __shared__ float xl[kS], sl[kS];
    __shared__ __align__(16) union { short G[576][40]; short H[2][288][40]; } U;
    __shared__ __align__(16) short W1s[32][40];

    int tid  = threadIdx.x;
    int lane = tid & 63;
    int wv   = tid >> 6;
    int mblk = blockIdx.x;
    int bz   = blockIdx.y;
    int bc   = img0 + bz;

    if (tid < 128) {
        xl[tid] = xn[(size_t)bc * kS + tid];
        int rr = tid >> 2, sg = tid & 3;
        *(uint4*)&W1s[rr][sg*8] = *(const uint4*)(w1b + rr*32 + sg*8);
    } else {
        sl[tid - 128] = sq[(size_t)bc * kS + (tid - 128)];
    }
    __syncthreads();

    // ---- Phase 1a: G ----
    #pragma unroll
    for (int it = 0; it < 3; ++it) {
        int idx = it * 256 + tid;
        if (idx >= 576) break;
        int trow = idx >> 6, hx = idx & 63;
        int iy = 8 * mblk + trow;
        unsigned int pk[16];
        #pragma unroll
        for (int j = 0; j < 16; ++j) pk[j] = 0u;
        if (iy < 64) {
            float xr[3], sr[3], xc[3], sc[3];
            #pragma unroll
            for (int k = 0; k < 3; ++k) {
                int iyy = 2*iy + k, ixx = 2*hx + k;
                bool vy = iyy < kS, vx = ixx < kS;
                xr[k] = vy ? xl[iyy] : 0.0f;  sr[k] = vy ? sl[iyy] : 0.0f;
                xc[k] = vx ? xl[ixx] : 0.0f;  sc[k] = vx ? sl[ixx] : 0.0f;
            }
            unsigned short gs[18];
            #pragma unroll
            for (int ky = 0; ky < 3; ++ky)
                #pragma unroll
                for (int kx = 0; kx < 3; ++kx) {
                    gs[ky*3+kx]   = f2bf(xr[ky]*xc[kx] - sr[ky]*sc[kx]);
                    gs[9+ky*3+kx] = f2bf(sr[ky]*xc[kx] - xr[ky]*sc[kx]);
                }
            #pragma unroll
            for (int j = 0; j < 9; ++j)
                pk[j] = (unsigned int)gs[2*j] | ((unsigned int)gs[2*j+1] << 16);
        }
        #pragma unroll
        for (int j = 0; j < 4; ++j) *(uint4*)&U.G[idx][j*8] = ((uint4*)pk)[j];
    }
    __syncthreads();

    // ---- Phase 1b: h1 = relu(G @ W1b^T + b1) ----
    f32x4 c1[9][2];
    bf16x8 w1f0 = *(const bf16x8*)&W1s[(lane & 15)][(lane>>4)*8];
    bf16x8 w1f1 = *(const bf16x8*)&W1s[16 + (lane & 15)][(lane>>4)*8];
    #pragma unroll
    for (int j = 0; j < 9; ++j) {
        int mt = 4*j + wv;
        bf16x8 af = *(const bf16x8*)&U.G[mt*16 + (lane & 15)][(lane>>4)*8];
        f32x4 zz = f32x4{0.f, 0.f, 0.f, 0.f};
        c1[j][0] = __builtin_amdgcn_mfma_f32_16x16x32_bf16(af, w1f0, zz, 0, 0, 0);
        c1[j][1] = __builtin_amdgcn_mfma_f32_16x16x32_bf16(af, w1f1, zz, 0, 0, 0);
    }
    __syncthreads();

    #pragma unroll
    for (int j = 0; j < 9; ++j) {
        int mt = 4*j + wv;
        #pragma unroll
        for (int h = 0; h < 2; ++h) {
            int oc = h*16 + (lane & 15);
            float bb = b1[oc];
            #pragma unroll
            for (int rg = 0; rg < 4; ++rg) {
                int pos = mt*16 + (lane>>4)*4 + rg;
                int trow = pos >> 6, hx = pos & 63;
                float v = fmaxf(c1[j][h][rg] + bb, 0.0f);
                if (8*mblk + trow >= 64) v = 0.0f;
                U.H[hx & 1][trow*32 + (hx >> 1)][oc] = (short)f2bf(v);
            }
        }
    }
    __syncthreads();

    // ---- Phase 2: conv2 GEMM, barrier-free (B direct from global) ----
    auto loadB2 = [&](int tap, bf16x8* dst) {
        #pragma unroll
        for (int ni = 0; ni < 4; ++ni) {
            int row = ni*16 + (lane & 15);
            dst[ni] = *(const bf16x8*)(wt2 + ((size_t)tap*64 + row)*32 + (lane>>4)*8);
        }
    };
    f32x4 acc[2][4];
    #pragma unroll
    for (int i = 0; i < 2; ++i)
        #pragma unroll
        for (int j = 0; j < 4; ++j) acc[i][j] = f32x4{0.f, 0.f, 0.f, 0.f};

    bf16x8 bcur[4], bnxt[4];
    loadB2(0, bcur);
    for (int tap = 0; tap < 9; ++tap) {
        if (tap + 1 < 9) loadB2(tap + 1, bnxt);
        int ky = tap / 3, kx = tap % 3;
        int trow = 2*wv + ky;
        bf16x8 af[2];
        #pragma unroll
        for (int mi = 0; mi < 2; ++mi) {
            int ocol = mi*16 + (lane & 15);
            int x = 2*ocol + kx;
            bf16x8 z = {0,0,0,0,0,0,0,0};
            af[mi] = (x < 64) ? *(const bf16x8*)&U.H[kx & 1][trow*32 + (x>>1)][(lane>>4)*8] : z;
        }
        #pragma unroll
        for (int mi = 0; mi < 2; ++mi)
            #pragma unroll
            for (int ni = 0; ni < 4; ++ni)
                acc[mi][ni] = __builtin_amdgcn_mfma_f32_16x16x32_bf16(af[mi], bcur[ni], acc[mi][ni], 0, 0, 0);
        #pragma unroll
        for (int ni = 0; ni < 4; ++ni) bcur[ni] = bnxt[ni];
    }

    int oy = 4*mblk + wv;
    #pragma unroll
    for (int ni = 0; ni < 4; ++ni) {
        int oc = ni*16 + (lane & 15);
        float b = b2[oc];
        #pragma unroll
        for (int mi = 0; mi < 2; ++mi)
            #pragma unroll
            for (int rg = 0; rg < 4; ++rg) {
                int ocol = 16*mi + (lane>>4)*4 + rg;
                float v = fmaxf(acc[mi][ni][rg] + b, 0.0f);
                out[(((size_t)bz*32 + oy)*32 + ocol)*64 + oc] = __float2bfloat16(v);
            }
    }
}

// ---- conv3: block = half-image; input-resident swizzled LDS tile; K-loop
// BARRIER-FREE (B fragments direct from wt3/L2 with distance-1 prefetch). ----
__global__ __launch_bounds__(256, 2)
void conv3_kernel(const bf16* __restrict__ h2, const bf16* __restrict__ wt3,
                  const float* __restrict__ b3, bf16* __restrict__ h3g) {
    __shared__ __align__(16) short T[34816];   // 68 KiB

    int tid  = threadIdx.x;
    int lane = tid & 63;
    int wv   = tid >> 6;
    int half = blockIdx.x;
    int img  = blockIdx.y;
    const bf16* h2i = h2 + (size_t)img * 65536;

    // stage input tile (rows half*16 .. half*16+16), swizzled
    for (int it = 0; it < 17; ++it) {
        int o = it*256 + tid;
        int r = o >> 8, c = o & 255;
        int ix = c >> 3, icq = c & 7;
        int gr = half*16 + r;
        uint4 v = {0u,0u,0u,0u};
        if (gr < 32) v = *(const uint4*)(h2i + gr*2048 + ix*64 + icq*8);
        int dst = ((((ix&1)*17 + r)*16 + (ix>>1))*8 + (icq ^ ((ix>>1)&7)))*8;
        *(uint4*)&T[dst] = v;
    }
    __syncthreads();

    auto loadB3 = [&](int s, bf16x8* dst) {
        int tap = s >> 1, icb = (s & 1) * 32;
        #pragma unroll
        for (int ni = 0; ni < 8; ++ni) {
            int row = ni*16 + (lane & 15);
            dst[ni] = *(const bf16x8*)(wt3 + ((size_t)tap*128 + row)*64 + icb + (lane>>4)*8);
        }
    };

    f32x4 acc[2][8];
    #pragma unroll
    for (int i = 0; i < 2; ++i)
        #pragma unroll
        for (int j = 0; j < 8; ++j) acc[i][j] = f32x4{0.f,0.f,0.f,0.f};

    bf16x8 bcur[8], bnxt[8];
    loadB3(0, bcur);
    for (int s = 0; s < 18; ++s) {
        if (s + 1 < 18) loadB3(s + 1, bnxt);
        int tap = s >> 1, icq0 = (s & 1) * 4;
        int ky = tap / 3, kx = tap % 3;
        bf16x8 af[2];
        #pragma unroll
        for (int mi = 0; mi < 2; ++mi) {
            int m = wv*32 + mi*16 + (lane & 15);
            int oyL = m >> 4, ox3 = m & 15;
            int iy = 2*oyL + ky, ix = 2*ox3 + kx;
            int par = ix & 1, colx = ix >> 1;
            int colc = colx > 15 ? 15 : colx;
            int addr = (((par*17 + iy)*16 + colc)*8 + ((icq0 + (lane>>4)) ^ (colc & 7)))*8;
            bf16x8 v = *(const bf16x8*)&T[addr];
            bf16x8 z = {0,0,0,0,0,0,0,0};
            af[mi] = (ix < 32) ? v : z;
        }
        #pragma unroll
        for (int mi = 0; mi < 2; ++mi)
            #pragma unroll
            for (int ni = 0; ni < 8; ++ni)
                acc[mi][ni] = __builtin_amdgcn_mfma_f32_16x16x32_bf16(af[mi], bcur[ni], acc[mi][ni], 0, 0, 0);
        #pragma unroll
        for (int ni = 0; ni < 8; ++ni) bcur[ni] = bnxt[ni];
    }

    // epilogue: write h3 (relu+bias) in conv4's swizzled layout
    bf16* h3o = h3g + (size_t)img * 32768;
    #pragma unroll
    for (int ni = 0; ni < 8; ++ni) {
        int oc3 = ni*16 + (lane & 15);
        float bb = b3[oc3];
        int kq = oc3 >> 3, ql = oc3 & 7;
        #pragma unroll
        for (int mi = 0; mi < 2; ++mi)
            #pragma unroll
            for (int rg = 0; rg < 4; ++rg) {
                int m = wv*32 + mi*16 + (lane>>4)*4 + rg;
                int oyL = m >> 4, ox3 = m & 15;
                int iy4 = half*8 + oyL;
                int par = ox3 & 1, col4 = ox3 >> 1;
                int slot = kq ^ col4;
                int off = ((par*16 + iy4)*8 + col4)*128 + slot*8 + ql;
                float v = fmaxf(acc[mi][ni][rg] + bb, 0.0f);
                h3o[off] = __float2bfloat16(v);
            }
    }
}

// ---- conv4: block = image; h3 LDS-resident (pre-swizzled, gld16-staged);
// K-loop BARRIER-FREE (B fragments direct from wt4/L2, distance-1 prefetch).
// Fused global-avg-pool epilogue. LDS = 64 KiB -> 2 blocks/CU. ----
__global__ __launch_bounds__(256, 2)
void conv4_kernel(const bf16* __restrict__ h3g, const bf16* __restrict__ wt4,
                  const float* __restrict__ b4, float* __restrict__ pooled,
                  int img0) {
    __shared__ __align__(16) short H3s[32768];  // 64 KiB

    int tid  = threadIdx.x;
    int lane = tid & 63;
    int wn   = tid >> 6;
    int img  = blockIdx.x;

    const char* h3b = (const char*)(h3g + (size_t)img * 32768);
    #pragma unroll
    for (int it = 0; it < 16; ++it)
        gld16(h3b + (it*256 + tid)*16, (char*)H3s + (it*256 + tid)*16);
    __syncthreads();

    auto loadB4 = [&](int s, bf16x8* dst) {
        int tap = s >> 2, icb = (s & 3) * 32;
        #pragma unroll
        for (int ni = 0; ni < 4; ++ni) {
            int row = wn*64 + ni*16 + (lane & 15);
            dst[ni] = *(const bf16x8*)(wt4 + ((size_t)tap*256 + row)*128 + icb + (lane>>4)*8);
        }
    };

    f32x4 acc[4][4];
    #pragma unroll
    for (int i = 0; i < 4; ++i)
        #pragma unroll
        for (int j = 0; j < 4; ++j) acc[i][j] = f32x4{0.f,0.f,0.f,0.f};

    bf16x8 bcur[4], bnxt[4];
    loadB4(0, bcur);
    for (int s = 0; s < 36; ++s) {
        if (s + 1 < 36) loadB4(s + 1, bnxt);
        int tap = s >> 2;
        int ky = tap / 3, kx = tap % 3;
        int kq0 = (s & 3)*4 + (lane >> 4);
        bf16x8 af[4];
        #pragma unroll
        for (int mi = 0; mi < 4; ++mi) {
            int m = mi*16 + (lane & 15);
            int oy = m >> 3, ox = m & 7;
            int iy = 2*oy + ky, ix = 2*ox + kx;
            bool valid = (iy < 16) && (ix < 16);
            int iyc = iy > 15 ? 15 : iy, ixc = ix > 15 ? 15 : ix;
            int par = ixc & 1, col = ixc >> 1;
            int slot = kq0 ^ col;
            int addr = ((par*16 + iyc)*8 + col)*128 + slot*8;
            bf16x8 v = *(const bf16x8*)&H3s[addr];
            bf16x8 z = {0,0,0,0,0,0,0,0};
            af[mi] = valid ? v : z;
        }
        #pragma unroll
        for (int mi = 0; mi < 4; ++mi)
            #pragma unroll
            for (int ni = 0; ni < 4; ++ni)
                acc[mi][ni] = __builtin_amdgcn_mfma_f32_16x16x32_bf16(af[mi], bcur[ni], acc[mi][ni], 0, 0, 0);
        #pragma unroll
        for (int ni = 0; ni < 4; ++ni) bcur[ni] = bnxt[ni];
    }

    // fused global-avg-pool: wave wn owns oc slice [wn*64, wn*64+64)
    #pragma unroll
    for (int ni = 0; ni < 4; ++ni) {
        int oc = wn*64 + ni*16 + (lane & 15);
        float bb = b4[oc];
        float ssum = 0.0f;
        #pragma unroll
        for (int mi = 0; mi < 4; ++mi)
            #pragma unroll
            for (int rg = 0; rg < 4; ++rg) ssum += fmaxf(acc[mi][ni][rg] + bb, 0.0f);
        ssum += __shfl_xor(ssum, 16);
        ssum += __shfl_xor(ssum, 32);
        if (lane < 16)
            pooled[((size_t)(img0 + img))*256 + oc] = ssum * (1.0f/64.0f);
    }
}

// ---- fused: mean over C (commutes with linear FC) + FC 256->128 ----
__global__ void poolfc_kernel(const float* __restrict__ pooled, const float* __restrict__ Wfc,
                              const float* __restrict__ bfc, float* __restrict__ out) {
    int b = blockIdx.x;
    int t = threadIdx.x;
    __shared__ float pm[256];
    #pragma unroll
    for (int q = 0; q < 2; ++q) {
        int k = q*128 + t;
        float s = 0.0f;
        #pragma unroll
        for (int c = 0; c < kC; ++c) s += pooled[((size_t)(b*kC + c))*256 + k];
        pm[k] = s * (1.0f/kC);
    }
    __syncthreads();
    float acc = bfc[t];
    for (int k = 0; k < 256; ++k) acc = fmaf(pm[k], Wfc[(size_t)k*kLatent + t], acc);
    out[(size_t)b*kLatent + t] = acc;
}

extern "C" void kernel_launch(void* const* d_in, const int* in_sizes, int n_in,
                              void* d_out, int out_size, void* d_ws, size_t ws_size,
                              hipStream_t stream) {
    const float* x_raw = (const float*)d_in[0];
    const float* W1 = (const float*)d_in[1];  const float* b1 = (const float*)d_in[2];
    const float* W2 = (const float*)d_in[3];  const float* b2 = (const float*)d_in[4];
    const float* W3 = (const float*)d_in[5];  const float* b3 = (const float*)d_in[6];
    const float* W4 = (const float*)d_in[7];  const float* b4 = (const float*)d_in[8];
    const float* Wfc = (const float*)d_in[9]; const float* bfc = (const float*)d_in[10];
    float* out = (float*)d_out;

    char* wsb = (char*)d_ws;
    float* xn     = (float*)(wsb);                      // 256 KiB
    float* sq     = (float*)(wsb + (256u<<10));         // 256 KiB
    float* pooled = (float*)(wsb + (512u<<10));         // 512 KiB
    bf16* Wt2     = (bf16*)(wsb + (1280u<<10));         // 36 KiB
    bf16* Wt3     = (bf16*)(wsb + (1316u<<10));         // 144 KiB
    bf16* Wt4     = (bf16*)(wsb + (1460u<<10));         // 576 KiB
    bf16* W1b     = (bf16*)(wsb + (2036u<<10));         // 2 KiB
    char* chunk_base = wsb + (2048u<<10);               // 2 MiB header

    const size_t perH2 = 32u*32u*64u*2u, perH3 = 64u<<10;
    const size_t perImg = perH2 + perH3;
    int chunk = 4;
    for (int c = 512; c >= 4; c >>= 1) {
        if ((2048u<<10) + (size_t)c * perImg <= ws_size) { chunk = c; break; }
    }

    gaf_stats_kernel<<<kBC, kS, 0, stream>>>(x_raw, xn, sq);
    wtrans_all_kernel<<<(388096 + 255)/256, 256, 0, stream>>>(W1, W2, W3, W4, W1b, Wt2, Wt3, Wt4);

    for (int img0 = 0; img0 < kBC; img0 += chunk) {
        int nimg = chunk;
        bf16* h2  = (bf16*)chunk_base;
        bf16* h3g = (bf16*)(chunk_base + (size_t)chunk * perH2);

        conv12_kernel<<<dim3(8, nimg), 256, 0, stream>>>(xn, sq, W1b, b1, Wt2, b2, h2, img0);
        conv3_kernel<<<dim3(2, nimg), 256, 0, stream>>>(h2, Wt3, b3, h3g);
        conv4_kernel<<<nimg, 256, 0, stream>>>(h3g, Wt4, b4, pooled, img0);
    }

    poolfc_kernel<<<kB, kLatent, 0, stream>>>(pooled, Wfc, bfc, out);
}